// Round 1
// 178.437 us; speedup vs baseline: 1.0013x; 1.0013x over previous
//
#include <hip/hip_runtime.h>
#include <hip/hip_bf16.h>

#define CODE_DIM 256
#define HIDDEN   128
#define HEADS    4
#define N_CODES  100000
#define N_SPEC   256

// ---- k2 config ----
#define K2_BLOCKS 768                     // exactly 3 blocks/CU at 3 waves/SIMD
#define K2_TPB    256
#define K2_WPB    4
#define K2_WAVES  (K2_BLOCKS * K2_WPB)    // 3072 waves; 4-5 tiles each, exact cover
#define WROWS     8                       // rows per tile
#define NTILES    (N_CODES / WROWS)       // 12500 exact
#define NSLOTS    64

// ---- ws layout (floats) ----
#define WS_V       0                       // v[h][d] : 1024
#define WS_CP      1024                    // c partials [64] (k1 block bx = h*16+dseg)
#define WS_SLOT    1104                    // 64 slots x 1028 (16B aligned)
#define SLOT_STRIDE 1028

#define WAITCNT_LGKM0 0xC07F   // lgkm=0, vmcnt=nowait (keeps prefetch loads in flight)

// K1 (64 blocks): v[h,d] = W[h,d,:]·a2[h]; c partials; zero slots.
__global__ void k1_prep(const float* __restrict__ pe, const float* __restrict__ W,
                        const float* __restrict__ b, const float* __restrict__ a,
                        float* __restrict__ ws) {
    const int bx = blockIdx.x;            // 64: (h, d-16th)
    const int h = bx >> 4, dseg = bx & 15;
    const int tid = threadIdx.x;
    const int dl = tid >> 4;              // 16 d-values per block
    const int q  = tid & 15;              // 16 k-chunks of 8 elems
    const int d  = dseg * 16 + dl;
    __shared__ float a_sh[2 * HIDDEN];
    __shared__ float cred[4];
    a_sh[tid] = a[h * 2 * HIDDEN + tid];
    __syncthreads();

    const float4* wr = (const float4*)(W + ((size_t)(h * CODE_DIM + d)) * HIDDEN + q * 8);
    float u = 0.f, v = 0.f;
#pragma unroll
    for (int j = 0; j < 2; ++j) {
        float4 wv = wr[j];
        int k = q * 8 + j * 4;
        u += wv.x * a_sh[k]     + wv.y * a_sh[k + 1]
           + wv.z * a_sh[k + 2] + wv.w * a_sh[k + 3];
        v += wv.x * a_sh[HIDDEN + k]     + wv.y * a_sh[HIDDEN + k + 1]
           + wv.z * a_sh[HIDDEN + k + 2] + wv.w * a_sh[HIDDEN + k + 3];
    }
#pragma unroll
    for (int off = 1; off < 16; off <<= 1) {
        u += __shfl_xor(u, off, 64);
        v += __shfl_xor(v, off, 64);
    }
    if (q == 0) ws[WS_V + h * CODE_DIM + d] = v;

    float cp = (q == 0) ? pe[d] * u : 0.f;
    if (dseg == 0 && tid < HIDDEN) cp += b[h * HIDDEN + tid] * (a_sh[tid] + a_sh[HIDDEN + tid]);
#pragma unroll
    for (int off = 32; off; off >>= 1) cp += __shfl_xor(cp, off, 64);
    if ((tid & 63) == 0) cred[tid >> 6] = cp;
    __syncthreads();
    if (tid == 0) ws[WS_CP + bx] = cred[0] + cred[1] + cred[2] + cred[3];

    // zero the 64 atomic slots (k2 depends on stream order)
    float4* z = (float4*)(ws + WS_SLOT);
    const int g = bx * 256 + tid;                 // 16384 threads
    const int nz = (NSLOTS * SLOT_STRIDE) / 4;    // 16448 float4s
    z[g] = make_float4(0.f, 0.f, 0.f, 0.f);
    if (g + 16384 < nz) z[g + 16384] = make_float4(0.f, 0.f, 0.f, 0.f);
}

// K2: streamed global->VGPR pass with register double-buffer prefetch;
// fused round-0 value-splitting butterfly; exact 3072-wave tile cover (no dups).
__global__ __launch_bounds__(K2_TPB, 3) void k2_main(const float* __restrict__ code,
                                                     float* __restrict__ ws) {
    __shared__ float t_sh[K2_WPB * 32];
    __shared__ float eps[K2_WPB * HEADS * CODE_DIM];   // 16 KB epilogue staging
    __shared__ float dsh[K2_WPB * HEADS];
    __shared__ float c_sh[HEADS];
    const int tid  = threadIdx.x;
    const int lane = tid & 63;
    const int w    = tid >> 6;
    const int bx   = blockIdx.x;
    const int wid  = bx * K2_WPB + w;

    // reduce the 64 c-partials (16 per head, contiguous)
    if (tid < 64) {
        float cpv = ws[WS_CP + tid];
#pragma unroll
        for (int off = 1; off < 16; off <<= 1) cpv += __shfl_xor(cpv, off, 64);
        if ((tid & 15) == 0) c_sh[tid >> 4] = cpv;
    }
    float4 vh[HEADS];
#pragma unroll
    for (int h = 0; h < HEADS; ++h)
        vh[h] = ((const float4*)(ws + WS_V + h * CODE_DIM))[lane];
    __syncthreads();
    const float cme = c_sh[lane & 3];      // this lane's head offset

    float4 acc0 = make_float4(0,0,0,0), acc1 = acc0, acc2 = acc0, acc3 = acc0;
    float dloc = 0.f;

    float4 xA[WROWS], xB[WROWS];

    auto prefetch = [&](float4* xr, int t) {
        const float4* rp = (const float4*)(code + (size_t)t * (WROWS * CODE_DIM));
#pragma unroll
        for (int r = 0; r < WROWS; ++r) xr[r] = rp[r * 64 + lane];   // coalesced 1KB/row
    };

    auto process = [&](const float4* x) {
        // dots fused with butterfly round 0: p[2r+hh] live (16 regs peak, not 32)
        float p[16];
        const bool hi0 = (lane & 1) != 0;
#pragma unroll
        for (int r = 0; r < WROWS; ++r) {
            float q0 = x[r].x * vh[0].x + x[r].y * vh[0].y + x[r].z * vh[0].z + x[r].w * vh[0].w;
            float q1 = x[r].x * vh[1].x + x[r].y * vh[1].y + x[r].z * vh[1].z + x[r].w * vh[1].w;
            float q2 = x[r].x * vh[2].x + x[r].y * vh[2].y + x[r].z * vh[2].z + x[r].w * vh[2].w;
            float q3 = x[r].x * vh[3].x + x[r].y * vh[3].y + x[r].z * vh[3].z + x[r].w * vh[3].w;
            float k0 = hi0 ? q1 : q0, s0 = hi0 ? q0 : q1;
            float k1 = hi0 ? q3 : q2, s1 = hi0 ? q2 : q3;
            p[2 * r]     = k0 + __shfl_xor(s0, 1, 64);
            p[2 * r + 1] = k1 + __shfl_xor(s1, 1, 64);
        }
        // remaining value-splitting rounds: 16 values -> lane l holds idx l&31
#pragma unroll
        for (int k = 1; k < 5; ++k) {
            const int m = 1 << k;
            const bool hi = (lane & m) != 0;
            const int nv = 16 >> k;
#pragma unroll
            for (int i = 0; i < nv; ++i) {
                float keep = hi ? p[2 * i + 1] : p[2 * i];
                float send = hi ? p[2 * i]     : p[2 * i + 1];
                p[i] = keep + __shfl_xor(send, m, 64);
            }
        }
        float tot = p[0] + __shfl_xor(p[0], 32, 64);   // lane l: full dot for (r,h)=l&31

        float e = tot + cme;
        e = (e >= 0.f) ? e : 0.2f * e;                 // leaky relu
        float t = __expf(e);                           // un-normalized softmax weight
        dloc += t;                                     // 2x duplicated (lanes & lanes^32)

        if (lane < 32) t_sh[w * 32 + lane] = t;        // banks 0..31, conflict-free
        __builtin_amdgcn_s_waitcnt(WAITCNT_LGKM0);     // lgkm only: keep prefetch in flight

        // weighted accumulation: lane owns cols 4l..4l+3 (x already in registers)
#pragma unroll
        for (int r = 0; r < WROWS; ++r) {
            float4 tr = *(const float4*)&t_sh[w * 32 + r * 4];   // uniform broadcast
            acc0.x += tr.x * x[r].x; acc0.y += tr.x * x[r].y; acc0.z += tr.x * x[r].z; acc0.w += tr.x * x[r].w;
            acc1.x += tr.y * x[r].x; acc1.y += tr.y * x[r].y; acc1.z += tr.y * x[r].z; acc1.w += tr.y * x[r].w;
            acc2.x += tr.z * x[r].x; acc2.y += tr.z * x[r].y; acc2.z += tr.z * x[r].z; acc2.w += tr.z * x[r].w;
            acc3.x += tr.w * x[r].x; acc3.y += tr.w * x[r].y; acc3.z += tr.w * x[r].z; acc3.w += tr.w * x[r].w;
        }
    };

    // software pipeline: prefetch(tile+stride) issued before process(tile)
    int t = wid;                    // every wave has >=1 tile (3072 < 12500)
    prefetch(xA, t);
    while (true) {
        int tn = t + K2_WAVES;
        if (tn < NTILES) prefetch(xB, tn);
        process(xA);
        if (tn >= NTILES) break;
        int tm = tn + K2_WAVES;
        if (tm < NTILES) prefetch(xA, tm);
        process(xB);
        if (tm >= NTILES) break;
        t = tm;
    }

    // denom: sum dloc over lanes sharing (lane&3); x2 duplication -> scale 0.5
#pragma unroll
    for (int off = 4; off < 64; off <<= 1) dloc += __shfl_xor(dloc, off, 64);
    if (lane < HEADS) dsh[w * HEADS + lane] = dloc * 0.5f;

    // stage per-wave acc, cross-wave reduce, one atomic slot-add per block
    *(float4*)&eps[w * 1024 +   0 + 4 * lane] = acc0;
    *(float4*)&eps[w * 1024 + 256 + 4 * lane] = acc1;
    *(float4*)&eps[w * 1024 + 512 + 4 * lane] = acc2;
    *(float4*)&eps[w * 1024 + 768 + 4 * lane] = acc3;
    __syncthreads();

    float* slot = ws + WS_SLOT + (size_t)(bx & (NSLOTS - 1)) * SLOT_STRIDE;
    for (int o = tid; o < HEADS * CODE_DIM; o += K2_TPB) {
        float s = eps[o] + eps[1024 + o] + eps[2048 + o] + eps[3072 + o];
        atomicAdd(slot + o, s);
    }
    if (tid < HEADS)
        atomicAdd(slot + HEADS * CODE_DIM + tid,
                  dsh[tid] + dsh[4 + tid] + dsh[8 + tid] + dsh[12 + tid]);
}

// K3 (16 blocks): reduce slots -> s[h][:]; normalize; GEMV agg = s@W + b -> mho
__global__ void k3_agg(const float* __restrict__ W, const float* __restrict__ b,
                       const float* __restrict__ ws, float* __restrict__ out) {
    const int bx = blockIdx.x;      // (h, k-quarter)
    const int h = bx >> 2, q = bx & 3;
    const int tid = threadIdx.x;
    __shared__ float s_sh[CODE_DIM];
    __shared__ float yred[8 * 32];
    __shared__ float den_sh;
    const float* slots = ws + WS_SLOT;

    if (tid < 64) {
        float dv = slots[(size_t)tid * SLOT_STRIDE + HEADS * CODE_DIM + h];
#pragma unroll
        for (int off = 32; off; off >>= 1) dv += __shfl_xor(dv, off, 64);
        if (tid == 0) den_sh = dv;
    }
    float su = 0.f;
#pragma unroll 8
    for (int s2 = 0; s2 < NSLOTS; ++s2)
        su += slots[(size_t)s2 * SLOT_STRIDE + h * CODE_DIM + tid];
    __syncthreads();
    s_sh[tid] = su / den_sh;
    __syncthreads();

    const int c = tid >> 5, kl = tid & 31;
    float y = 0.f;
    const float* wp = W + ((size_t)(h * CODE_DIM + c * 32)) * HIDDEN + q * 32 + kl;
#pragma unroll 8
    for (int d = 0; d < 32; ++d) y += s_sh[c * 32 + d] * wp[(size_t)d * HIDDEN];
    yred[c * 32 + kl] = y;
    __syncthreads();
    if (tid < 32) {
        float t = 0.f;
#pragma unroll
        for (int cc = 0; cc < 8; ++cc) t += yred[cc * 32 + tid];
        out[N_SPEC + h * HIDDEN + q * 32 + tid] = t + b[h * HIDDEN + q * 32 + tid];
    }
}

// K4: specialty_logits = Wc @ mho + bc; one wave per logit
__global__ void k4_logits(const float* __restrict__ Wc, const float* __restrict__ bc,
                          float* __restrict__ out) {
    const int lane = threadIdx.x & 63;
    const int wv   = threadIdx.x >> 6;
    const int i    = blockIdx.x * 4 + wv;
    const float4* wr  = (const float4*)(Wc + (size_t)i * (HEADS * HIDDEN));
    const float4* mh4 = (const float4*)(out + N_SPEC);
    float4 wa = wr[lane],      ma = mh4[lane];
    float4 wb = wr[64 + lane], mb = mh4[64 + lane];
    float pp = wa.x * ma.x + wa.y * ma.y + wa.z * ma.z + wa.w * ma.w
             + wb.x * mb.x + wb.y * mb.y + wb.z * mb.z + wb.w * mb.w;
#pragma unroll
    for (int off = 32; off; off >>= 1) pp += __shfl_xor(pp, off, 64);
    if (lane == 0) out[i] = pp + bc[i];
}

extern "C" void kernel_launch(void* const* d_in, const int* in_sizes, int n_in,
                              void* d_out, int out_size, void* d_ws, size_t ws_size,
                              hipStream_t stream) {
    const float* pe   = (const float*)d_in[0];
    const float* code = (const float*)d_in[1];
    const float* W    = (const float*)d_in[2];
    const float* b    = (const float*)d_in[3];
    const float* a    = (const float*)d_in[4];
    const float* Wc   = (const float*)d_in[5];
    const float* bc   = (const float*)d_in[6];
    float* out = (float*)d_out;
    float* ws  = (float*)d_ws;

    k1_prep<<<64, 256, 0, stream>>>(pe, W, b, a, ws);
    k2_main<<<K2_BLOCKS, K2_TPB, 0, stream>>>(code, ws);
    k3_agg<<<16, 256, 0, stream>>>(W, b, ws, out);
    k4_logits<<<64, 256, 0, stream>>>(Wc, bc, out);
}